// Round 9
// baseline (923.515 us; speedup 1.0000x reference)
//
#include <hip/hip_runtime.h>
#include <hip/hip_bf16.h>
#include <float.h>
#include <math.h>
#include <stdint.h>

constexpr int B_   = 8;
constexpr int N_   = 785;
constexpr int C_   = 768;
constexpr int H_   = 12;
constexpr int DH_  = 64;
constexpr int NT_  = 393;
constexpr int QKVC = 3 * C_;   // 2304
constexpr int BN   = B_ * N_;  // 6280
constexpr int BT   = B_ * NT_; // 3144
constexpr int MSEL = N_ - 1;   // 784
constexpr float  SCALE_F = 0.125f;
constexpr double LNEPS   = 1e-5;
constexpr double SMEPS   = 1e-6;

#define DEV static __device__ __forceinline__

typedef __hip_bfloat16 bf16;
typedef __attribute__((ext_vector_type(8))) short frag8;
typedef __attribute__((ext_vector_type(4))) float facc4;

DEV short f2b(float v) { return (short)__hip_bfloat16_raw(__float2bfloat16(v)).x; }
DEV float b2f(short s) {
  union { unsigned int u; float f; } cv;
  cv.u = ((unsigned int)(unsigned short)s) << 16;
  return cv.f;
}
DEV float gelu_exact(float v) { return 0.5f * v * (1.0f + erff(v * 0.70710678118654752f)); }

// ---------------- block reductions ----------------
DEV double blockReduceSumD(double v, double* scratch, int nw) {
#pragma unroll
  for (int o = 32; o; o >>= 1) v += __shfl_xor(v, o);
  int lane = threadIdx.x & 63, wid = threadIdx.x >> 6;
  __syncthreads();
  if (lane == 0) scratch[wid] = v;
  __syncthreads();
  double r = scratch[0];
  for (int i = 1; i < nw; i++) r += scratch[i];
  return r;
}
DEV double blockReduceMaxD(double v, double* scratch, int nw) {
#pragma unroll
  for (int o = 32; o; o >>= 1) v = fmax(v, __shfl_xor(v, o));
  int lane = threadIdx.x & 63, wid = threadIdx.x >> 6;
  __syncthreads();
  if (lane == 0) scratch[wid] = v;
  __syncthreads();
  double r = scratch[0];
  for (int i = 1; i < nw; i++) r = fmax(r, scratch[i]);
  return r;
}
DEV float blockReduceSumF(float v, float* scratch, int nw) {
#pragma unroll
  for (int o = 32; o; o >>= 1) v += __shfl_xor(v, o);
  int lane = threadIdx.x & 63, wid = threadIdx.x >> 6;
  __syncthreads();
  if (lane == 0) scratch[wid] = v;
  __syncthreads();
  float r = scratch[0];
  for (int i = 1; i < nw; i++) r += scratch[i];
  return r;
}
DEV float blockReduceMaxF(float v, float* scratch, int nw) {
#pragma unroll
  for (int o = 32; o; o >>= 1) v = fmaxf(v, __shfl_xor(v, o));
  int lane = threadIdx.x & 63, wid = threadIdx.x >> 6;
  __syncthreads();
  if (lane == 0) scratch[wid] = v;
  __syncthreads();
  float r = scratch[0];
  for (int i = 1; i < nw; i++) r = fmaxf(r, scratch[i]);
  return r;
}

// ---------------- LN1: x(f32) -> xn64 (fp64 scoring) + xn_bf (bf16 value) --------
__global__ __launch_bounds__(256) void ln1_kernel(
    const float* __restrict__ x, const float* __restrict__ w, const float* __restrict__ b,
    double* __restrict__ xn64, bf16* __restrict__ xnb) {
  int row = blockIdx.x;
  int t = threadIdx.x;
  __shared__ double scr[8];
  const float* xr = x + (size_t)row * C_;
  double vals[3];
#pragma unroll
  for (int i = 0; i < 3; i++) vals[i] = (double)xr[t + i * 256];
  double s = vals[0] + vals[1] + vals[2];
  s = blockReduceSumD(s, scr, 4);
  double mean = s / (double)C_;
  double vs = 0.0;
#pragma unroll
  for (int i = 0; i < 3; i++) { double d = vals[i] - mean; vs += d * d; }
  vs = blockReduceSumD(vs, scr, 4);
  double inv = 1.0 / sqrt(vs / (double)C_ + LNEPS);
#pragma unroll
  for (int i = 0; i < 3; i++) {
    int c = t + i * 256;
    double o = (vals[i] - mean) * inv * (double)w[c] + (double)b[c];
    xn64[(size_t)row * C_ + c] = o;
    xnb[(size_t)row * C_ + c] = __float2bfloat16((float)o);
  }
}

// ---------------- weight transpose+convert: W[K][N] f32 -> Wt[N][K] bf16 ---------
__global__ __launch_bounds__(256) void transpose_bf16(
    const float* __restrict__ W, bf16* __restrict__ Wt, int K, int N) {
  __shared__ float tile[32][33];
  int k0 = blockIdx.y * 32, n0 = blockIdx.x * 32;
  int tx = threadIdx.x & 31, ty = threadIdx.x >> 5;
  for (int i = ty; i < 32; i += 8) {
    int k = k0 + i, n = n0 + tx;
    tile[i][tx] = (k < K && n < N) ? W[(size_t)k * N + n] : 0.f;
  }
  __syncthreads();
  for (int i = ty; i < 32; i += 8) {
    int n = n0 + i, k = k0 + tx;
    if (n < N && k < K) Wt[(size_t)n * K + k] = __float2bfloat16(tile[tx][i]);
  }
}

// ---------------- 128x128-tile bf16 MFMA GEMM ----------------
// 4 waves, each owns a 64x64 quadrant (wr,wc), acc[4][4] of 16x16 fragments.
// Fragment/lane mapping identical to the verified 64^2 kernel (A: row=l&15,
// k=(l>>4)*8; C/D: row=i*16+(l>>4)*4+reg, col=j*16+(l&15)), offset by quadrant.
// Epilogue: bias/rowscale -> f32 Cc, or (gelu_bf set) gelu(acc+bias) -> bf16.
__global__ __launch_bounds__(256) void gemm128(
    const bf16* __restrict__ A, const bf16* __restrict__ Bt,
    float* __restrict__ Cc, const float* __restrict__ bias,
    const float* __restrict__ rowscale, int M, int K, int Ncols,
    bf16* __restrict__ gelu_bf) {
  __shared__ short As[128][40];
  __shared__ short Bs[128][40];
  const short* Ap = (const short*)A;
  const short* Bp = (const short*)Bt;
  int t = threadIdx.x;
  int n0 = blockIdx.x * 128;
  int m0 = blockIdx.y * 128;
  int w = t >> 6, l = t & 63;
  int wr = w >> 1, wc = w & 1;
  int srow = t >> 1;
  int koff = (t & 1) * 16;
  int fr = l & 15, fk = (l >> 4) * 8;
  facc4 acc[4][4] = {};
  for (int k0 = 0; k0 < K; k0 += 32) {
    int4 av0 = make_int4(0, 0, 0, 0), av1 = make_int4(0, 0, 0, 0);
    if (m0 + srow < M) {
      const short* ap = Ap + (size_t)(m0 + srow) * K + k0 + koff;
      av0 = *(const int4*)ap;
      av1 = *(const int4*)(ap + 8);
    }
    const short* bp = Bp + (size_t)(n0 + srow) * K + k0 + koff;
    int4 bv0 = *(const int4*)bp;
    int4 bv1 = *(const int4*)(bp + 8);
    *(int4*)(&As[srow][koff])     = av0;
    *(int4*)(&As[srow][koff + 8]) = av1;
    *(int4*)(&Bs[srow][koff])     = bv0;
    *(int4*)(&Bs[srow][koff + 8]) = bv1;
    __syncthreads();
    frag8 af[4], bf[4];
#pragma unroll
    for (int i = 0; i < 4; i++) af[i] = *(frag8*)(&As[wr * 64 + i * 16 + fr][fk]);
#pragma unroll
    for (int j = 0; j < 4; j++) bf[j] = *(frag8*)(&Bs[wc * 64 + j * 16 + fr][fk]);
#pragma unroll
    for (int i = 0; i < 4; i++)
#pragma unroll
      for (int j = 0; j < 4; j++)
        acc[i][j] = __builtin_amdgcn_mfma_f32_16x16x32_bf16(af[i], bf[j], acc[i][j], 0, 0, 0);
    __syncthreads();
  }
#pragma unroll
  for (int i = 0; i < 4; i++) {
#pragma unroll
    for (int reg = 0; reg < 4; reg++) {
      int row = m0 + wr * 64 + i * 16 + (l >> 4) * 4 + reg;
      if (row >= M) continue;
      float rs = rowscale ? rowscale[row] : 1.f;
#pragma unroll
      for (int j = 0; j < 4; j++) {
        int col = n0 + wc * 64 + j * 16 + fr;
        float v = acc[i][j][reg];
        if (bias) v += bias[col];
        if (gelu_bf) {
          gelu_bf[(size_t)row * Ncols + col] = __float2bfloat16(gelu_exact(v));
        } else {
          v *= rs;
          Cc[(size_t)row * Ncols + col] = v;
        }
      }
    }
  }
}

// ---------------- q0 (row-0 query, fp64): grid (B, 12), coalesced W reads --------
__global__ __launch_bounds__(256) void q0_kernel(
    const double* __restrict__ xn64, const float* __restrict__ qkvw,
    const float* __restrict__ policy, double* __restrict__ q064) {
  int b = blockIdx.x;
  int jc = blockIdx.y;             // 0..11 -> 64 outputs
  int t = threadIdx.x;
  int jl = t & 63, ks = t >> 6;    // 4 k-slices of 192
  __shared__ double x0[C_];
  __shared__ double part[4][64];
  for (int i = t; i < C_; i += 256) x0[i] = xn64[(size_t)(b * N_) * C_ + i];
  __syncthreads();
  int j = jc * 64 + jl;
  const float* wp = qkvw + j;
  double a = 0.0;
  int c0 = ks * 192;
#pragma unroll 8
  for (int c = c0; c < c0 + 192; c++) a += x0[c] * (double)wp[(size_t)c * QKVC];
  part[ks][jl] = a;
  __syncthreads();
  if (t < 64) {
    double pol = (double)policy[b * N_];
    q064[b * C_ + jc * 64 + t] =
        (part[0][t] + part[1][t] + part[2][t] + part[3][t]) * pol;
  }
}

// ---------------- g[b,h,c] (fp64) ----------------
__global__ __launch_bounds__(256) void g_kernel(
    const double* __restrict__ q064, const float* __restrict__ qkvw,
    double* __restrict__ g64) {
  int bh = blockIdx.x;
  int b = bh / H_, h = bh % H_;
  int t = threadIdx.x;
  __shared__ double qh[DH_];
  if (t < DH_) qh[t] = q064[b * C_ + h * DH_ + t];
  __syncthreads();
  for (int c = t; c < C_; c += 256) {
    const float* wp = qkvw + (size_t)c * QKVC + C_ + h * DH_;
    double a = 0.0;
#pragma unroll 8
    for (int d = 0; d < DH_; d++) a += qh[d] * (double)wp[d];
    g64[(size_t)bh * C_ + c] = a;
  }
}

// ---------------- row-0 logits fp64: wave-per-head, shuffle reduce ---------------
__global__ __launch_bounds__(256) void logits_kernel(
    const double* __restrict__ xn64, const double* __restrict__ g64,
    const float* __restrict__ policy, double* __restrict__ l64) {
  int row = blockIdx.x;
  int b = row / N_;
  int n = row % N_;
  int t = threadIdx.x;
  int w = t >> 6, lane = t & 63;
  __shared__ double xr[C_];
  for (int i = t; i < C_; i += 256) xr[i] = xn64[(size_t)row * C_ + i];
  __syncthreads();
  double pol = (double)policy[row];
#pragma unroll
  for (int hh = 0; hh < 3; hh++) {
    int h = w + hh * 4;
    const double* gp = g64 + (size_t)(b * H_ + h) * C_;
    double p = 0.0;
#pragma unroll 4
    for (int i = lane; i < C_; i += 64) p += xr[i] * gp[i];
#pragma unroll
    for (int o = 32; o; o >>= 1) p += __shfl_xor(p, o);
    if (lane == 0) l64[(size_t)(b * H_ + h) * N_ + n] = 0.125 * pol * p;
  }
}

// ---------------- ||v||^2 fp64: verified round-4 kernel (fp64 roofline ~253us) ---
__global__ __launch_bounds__(256) void vnorm_kernel(
    const double* __restrict__ xn64, const float* __restrict__ qkvw,
    const float* __restrict__ policy, double* __restrict__ vnorm2) {
  __shared__ double scr[8];
  int r0 = blockIdx.x * 8;
  int t = threadIdx.x;
  double acc[8][3] = {};
  const double* xb = xn64 + (size_t)r0 * C_;
  for (int c = 0; c < C_; c += 2) {
    const float* wp0 = qkvw + (size_t)c * QKVC + 2 * C_;
    const float* wp1 = wp0 + QKVC;
    double w00 = (double)wp0[t], w01 = (double)wp0[t + 256], w02 = (double)wp0[t + 512];
    double w10 = (double)wp1[t], w11 = (double)wp1[t + 256], w12 = (double)wp1[t + 512];
#pragma unroll
    for (int r = 0; r < 8; r++) {
      double x0 = xb[(size_t)r * C_ + c];
      double x1 = xb[(size_t)r * C_ + c + 1];
      acc[r][0] += x0 * w00; acc[r][1] += x0 * w01; acc[r][2] += x0 * w02;
      acc[r][0] += x1 * w10; acc[r][1] += x1 * w11; acc[r][2] += x1 * w12;
    }
  }
#pragma unroll
  for (int r = 0; r < 8; r++) {
    double p = acc[r][0] * acc[r][0] + acc[r][1] * acc[r][1] + acc[r][2] * acc[r][2];
    double s = blockReduceSumD(p, scr, 4);
    if (t == 0) {
      double pol = (double)policy[r0 + r];
      vnorm2[r0 + r] = s * pol * pol;
    }
  }
}

// ---------------- row-0 softmax fp64 (in place) ----------------
__global__ __launch_bounds__(256) void softmax0_kernel(
    double* __restrict__ l64, const float* __restrict__ policy) {
  int bh = blockIdx.x;
  int b = bh / H_;
  double* lp = l64 + (size_t)bh * N_;
  __shared__ double scr[8];
  int t = threadIdx.x;
  double mx = -1e300;
  for (int n = t; n < N_; n += 256) mx = fmax(mx, lp[n]);
  mx = blockReduceMaxD(mx, scr, 4);
  double ssum = 0.0;
  for (int n = t; n < N_; n += 256) {
    double pol = (double)policy[b * N_ + n];
    double w = (n == 0) ? 1.0 : pol;
    double e = exp(lp[n] - mx) * w;
    lp[n] = e;
    ssum += e;
  }
  ssum = blockReduceSumD(ssum, scr, 4);
  double denom = ssum + SMEPS;
  double addc = SMEPS / (double)N_;
  for (int n = t; n < N_; n += 256) lp[n] = (lp[n] + addc) / denom;
}

// ---------------- selection fp64, paranoid-simple ----------------
__global__ __launch_bounds__(1024) void select_kernel(
    const double* __restrict__ p0, const double* __restrict__ vnorm2,
    int* __restrict__ selidx, float* __restrict__ poln, float* __restrict__ out_pol) {
  int b = blockIdx.x;
  int t = threadIdx.x;
  __shared__ double sigv[MSEL];
  __shared__ double svals[MSEL];
  __shared__ double nc[MSEL];
  __shared__ int    ord[MSEL];
  __shared__ int    pick[MSEL];
  __shared__ int    spick[MSEL];
  __shared__ int    uq[MSEL];
  __shared__ int    suq[MSEL];
  __shared__ double sh_ys;

  if (t < MSEL) {
    int n = t + 1;
    double s = 0.0;
#pragma unroll
    for (int h = 0; h < H_; h++) s += p0[(size_t)(b * H_ + h) * N_ + n];
    sigv[t] = s * sqrt(vnorm2[b * N_ + n]);
  }
  __syncthreads();
  if (t < MSEL) {
    double v = sigv[t];
    int rank = 0;
    for (int i = 0; i < MSEL; i++) {
      double vi = sigv[i];
      rank += (vi < v) || (vi == v && i < t);
    }
    ord[rank] = t;
    svals[rank] = v;
  }
  __syncthreads();
  if (t == 0) {
    double a = 0.0;
    for (int i = 0; i < MSEL; i++) { a += svals[i]; svals[i] = a; }
  }
  __syncthreads();
  {
    double c0 = svals[0], cN = svals[MSEL - 1];
    if (t < MSEL) nc[t] = (svals[t] - c0) / (cN - c0);
  }
  __syncthreads();
  if (t == 0) {
    double m = 1e300;
    for (int i = 0; i < MSEL; i++) {
      double v = nc[i];
      if (v == 0.0) v += 100000000.0;
      m = fmin(m, v);
    }
    sh_ys = m;
  }
  __syncthreads();
  if (t < MSEL) {
    double s = sh_ys;
    double ysj = (t == MSEL - 1) ? 1.0 : (double)t / 783.0;
    double y = s + (ysj * 783.0 - s * (double)t) / 783.0;
    double bd = 1e300;
    int bi = 0;
    for (int i = 0; i < MSEL; i++) {
      double d = fabs(y - nc[i]);
      if (d < bd) { bd = d; bi = i; }
    }
    pick[t] = bi;
  }
  __syncthreads();
  if (t < MSEL) {
    int p = pick[t];
    int rank = 0;
    for (int i = 0; i < MSEL; i++) {
      int pi = pick[i];
      rank += (pi < p) || (pi == p && i < t);
    }
    spick[rank] = p;
  }
  __syncthreads();
  if (t < MSEL) {
    int s = spick[t];
    int nxt = (t < MSEL - 1) ? spick[t + 1] : 1;
    uq[t] = (nxt == s) ? MSEL : s;
  }
  __syncthreads();
  if (t < MSEL) {
    int u = uq[t];
    int rank = 0;
    for (int i = 0; i < MSEL; i++) {
      int ui = uq[i];
      rank += (ui < u) || (ui == u && i < t);
    }
    suq[rank] = u;
  }
  __syncthreads();
  if (t < NT_) {
    int sel, polI;
    if (t == 0) { sel = 0; polI = 1; }
    else {
      int ut = suq[t - 1];
      polI = (ut != MSEL) ? 1 : 0;
      sel = polI ? (ord[ut] + 1) : -1;
    }
    selidx[b * NT_ + t] = sel;
    poln[b * NT_ + t] = (float)polI;
    out_pol[b * NT_ + t] = (float)polI;
  }
}

// ---------------- fused flash attention, bf16 MFMA ----------------
__global__ __launch_bounds__(256) void flash_kernel(
    const float* __restrict__ qkv, const int* __restrict__ selidx,
    const float* __restrict__ policy, bf16* __restrict__ attn_bf) {
  int bh = blockIdx.y;
  int b = bh / H_, h = bh % H_;
  int j0 = blockIdx.x * 64;
  int t = threadIdx.x;
  int w = t >> 6, l = t & 63;
  __shared__ short Qs[64][72];   // [j][d]  A-operand layout
  __shared__ short Ks[64][72];   // [n][d]  B-operand layout (Bt-style)
  __shared__ short Ps[64][72];   // [j][n]  A-operand for PV
  __shared__ short Vs[64][72];   // [d][n]  B-operand for PV (V transposed)
  __shared__ float pol_s[64];
  __shared__ float Vsum[64];

  {
    int jr = t >> 2, d0 = (t & 3) * 16;
    int j = j0 + jr;
    int r = (j < NT_) ? selidx[b * NT_ + j] : -1;
    if (r < 0) r = 0;
    const float* qp = qkv + (size_t)(b * N_ + r) * QKVC + h * DH_ + d0;
#pragma unroll
    for (int i = 0; i < 16; i++) Qs[jr][d0 + i] = f2b(qp[i]);
  }
  if (t < 64) Vsum[t] = 0.f;

  int frow = l & 15, fk = (l >> 4) * 8;
  int base_r = w * 16 + (l >> 4) * 4;
  int coln = l & 15;

  int rrow[4];
#pragma unroll
  for (int r = 0; r < 4; r++) {
    int j = j0 + base_r + r;
    rrow[r] = (j < NT_) ? selidx[b * NT_ + j] : -1;
  }
  float m_run[4] = {-1e30f, -1e30f, -1e30f, -1e30f};
  float s_run[4] = {0.f, 0.f, 0.f, 0.f};
  facc4 Oacc[4] = {{0, 0, 0, 0}, {0, 0, 0, 0}, {0, 0, 0, 0}, {0, 0, 0, 0}};

  for (int n0 = 0; n0 < 832; n0 += 64) {
    {  // stage K tile
      int nr = t >> 2, d0 = (t & 3) * 16;
      int n = n0 + nr;
      bool ok = n < N_;
      const float* kp = qkv + (size_t)(b * N_ + (ok ? n : 0)) * QKVC + C_ + h * DH_ + d0;
#pragma unroll
      for (int i = 0; i < 16; i++) Ks[nr][d0 + i] = f2b(ok ? kp[i] : 0.f);
    }
    if (t < 64) {
      int n = n0 + t;
      pol_s[t] = (n < N_) ? policy[b * N_ + n] : 0.f;
    }
    __syncthreads();  // B1: K/pol visible (and prev-tile PV fully done)

    facc4 Sacc[4] = {{0, 0, 0, 0}, {0, 0, 0, 0}, {0, 0, 0, 0}, {0, 0, 0, 0}};
#pragma unroll
    for (int k0 = 0; k0 < 64; k0 += 32) {
      frag8 a = *(frag8*)(&Qs[w * 16 + frow][k0 + fk]);
#pragma unroll
      for (int nt = 0; nt < 4; nt++) {
        frag8 bb = *(frag8*)(&Ks[nt * 16 + frow][k0 + fk]);
        Sacc[nt] = __builtin_amdgcn_mfma_f32_16x16x32_bf16(a, bb, Sacc[nt], 0, 0, 0);
      }
    }
    float S[4][4];
    float tmax[4] = {-1e30f, -1e30f, -1e30f, -1e30f};
#pragma unroll
    for (int nt = 0; nt < 4; nt++) {
#pragma unroll
      for (int r = 0; r < 4; r++) {
        int n = n0 + nt * 16 + coln;
        float v = (n < N_) ? Sacc[nt][r] * SCALE_F : -1e30f;
        S[nt][r] = v;
        tmax[r] = fmaxf(tmax[r], v);
      }
    }
#pragma unroll
    for (int o = 1; o < 16; o <<= 1) {
#pragma unroll
      for (int r = 0; r < 4; r++) tmax[r] = fmaxf(tmax[r], __shfl_xor(tmax[r], o));
    }
    float m_new[4], scl[4], psum[4];
#pragma unroll
    for (int r = 0; r < 4; r++) {
      m_new[r] = fmaxf(m_run[r], tmax[r]);
      scl[r] = expf(m_run[r] - m_new[r]);
      psum[r] = 0.f;
    }
#pragma unroll
    for (int nt = 0; nt < 4; nt++) {
      float pol = pol_s[nt * 16 + coln];
      int n = n0 + nt * 16 + coln;
#pragma unroll
      for (int r = 0; r < 4; r++) {
        float wgt = (n == rrow[r]) ? 1.f : pol;
        float e = expf(S[nt][r] - m_new[r]) * wgt;
        S[nt][r] = e;
        psum[r] += e;
      }
    }
#pragma unroll
    for (int o = 1; o < 16; o <<= 1) {
#pragma unroll
      for (int r = 0; r < 4; r++) psum[r] += __shfl_xor(psum[r], o);
    }
#pragma unroll
    for (int r = 0; r < 4; r++) {
      s_run[r] = s_run[r] * scl[r] + psum[r];
      m_run[r] = m_new[r];
    }
    __syncthreads();  // B2: QK reads of Ks done; Ps/Vs free to overwrite

#pragma unroll
    for (int nt = 0; nt < 4; nt++) {
#pragma unroll
      for (int r = 0; r < 4; r++) Ps[base_r + r][nt * 16 + coln] = f2b(S[nt][r]);
    }
    {  // stage V transposed [d][n]
      int nr = t >> 2, d0 = (t & 3) * 16;
      int n = n0 + nr;
      bool ok = n < N_;
      const float* vp = qkv + (size_t)(b * N_ + (ok ? n : 0)) * QKVC + 2 * C_ + h * DH_ + d0;
#pragma unroll
      for (int i = 0; i < 16; i++) Vs[d0 + i][nr] = f2b(ok ? vp[i] : 0.f);
    }
    __syncthreads();  // B3: Ps/Vs visible

    if (t < 64) {
      float a = 0.f;
#pragma unroll 16
      for (int k = 0; k < 64; k++) a += b2f(Vs[t][k]);
      Vsum[t] += a;
    }
#pragma unroll
    for (int dt = 0; dt < 4; dt++) {
#pragma unroll
      for (int r = 0; r < 4; r++) Oacc[dt][r] *= scl[r];
    }
#pragma unroll
    for (int k0 = 0; k0 < 64; k0 += 32) {
      frag8 a = *(frag8*)(&Ps[w * 16 + frow][k0 + fk]);
#pragma unroll
      for (int dt = 0; dt < 4; dt++) {
        frag8 bb = *(frag8*)(&Vs[dt * 16 + frow][k0 + fk]);
        Oacc[dt] = __builtin_amdgcn_mfma_f32_16x16x32_bf16(a, bb, Oacc[dt], 0, 0, 0);
      }
    }
  }
  __syncthreads();  // Vsum final values visible to all
  float addc = 1e-6f / (float)N_;
#pragma unroll
  for (int r = 0; r < 4; r++) {
    int j = j0 + base_r + r;
    if (j >= NT_) continue;
    float denom = s_run[r] + 1e-6f;
#pragma unroll
    for (int dt = 0; dt < 4; dt++) {
      int d = dt * 16 + coln;
      float val = (Oacc[dt][r] + addc * Vsum[d]) / denom;
      attn_bf[(size_t)(b * NT_ + j) * C_ + h * DH_ + d] = __float2bfloat16(val);
    }
  }
}

// ---------------- epilogues ----------------
__global__ __launch_bounds__(256) void e2_kernel(
    const float* __restrict__ cbuf, const float* __restrict__ poln,
    const int* __restrict__ selidx, const float* __restrict__ x, float* __restrict__ x2) {
  int row = blockIdx.x;
  int t = threadIdx.x;
  int b = row / NT_;
  int r = selidx[row];
  float pn = poln[row];
  for (int i = t; i < C_; i += 256) {
    float sx = (r >= 0) ? x[(size_t)(b * N_ + r) * C_ + i] : 0.f;
    x2[(size_t)row * C_ + i] = sx + cbuf[(size_t)row * C_ + i] * pn;
  }
}

__global__ __launch_bounds__(256) void ln2_kernel(
    const float* __restrict__ xin, const float* __restrict__ w, const float* __restrict__ b,
    bf16* __restrict__ xoutb) {
  int row = blockIdx.x;
  int t = threadIdx.x;
  __shared__ float scr[8];
  const float* xr = xin + (size_t)row * C_;
  float vals[3];
#pragma unroll
  for (int i = 0; i < 3; i++) vals[i] = xr[t + i * 256];
  float s = vals[0] + vals[1] + vals[2];
  s = blockReduceSumF(s, scr, 4);
  float mean = s / (float)C_;
  float vs = 0.f;
#pragma unroll
  for (int i = 0; i < 3; i++) { float d = vals[i] - mean; vs += d * d; }
  vs = blockReduceSumF(vs, scr, 4);
  float sd = sqrtf(vs / (float)C_ + 1e-5f);
#pragma unroll
  for (int i = 0; i < 3; i++) {
    int c = t + i * 256;
    xoutb[(size_t)row * C_ + c] =
        __float2bfloat16((vals[i] - mean) / sd * w[c] + b[c]);
  }
}

__global__ __launch_bounds__(256) void e4_kernel(
    const float* __restrict__ x2, const float* __restrict__ cbuf,
    const float* __restrict__ poln, float* __restrict__ out) {
  int row = blockIdx.x;
  int t = threadIdx.x;
  float pn = poln[row];
  for (int i = t; i < C_; i += 256) {
    float v = x2[(size_t)row * C_ + i] + cbuf[(size_t)row * C_ + i] * pn;
    out[(size_t)row * C_ + i] = v;
  }
}

// ---------------- launcher ----------------
extern "C" void kernel_launch(void* const* d_in, const int* in_sizes, int n_in,
                              void* d_out, int out_size, void* d_ws, size_t ws_size,
                              hipStream_t stream) {
  const float* x      = (const float*)d_in[0];
  const float* policy = (const float*)d_in[1];
  const float* n1w    = (const float*)d_in[2];
  const float* n1b    = (const float*)d_in[3];
  const float* qkvw   = (const float*)d_in[4];
  const float* projw  = (const float*)d_in[5];
  const float* projb  = (const float*)d_in[6];
  const float* n2w    = (const float*)d_in[7];
  const float* n2b    = (const float*)d_in[8];
  const float* fc1w   = (const float*)d_in[9];
  const float* fc1b   = (const float*)d_in[10];
  const float* fc2w   = (const float*)d_in[11];
  const float* fc2b   = (const float*)d_in[12];

  char* ws = (char*)d_ws;
  size_t off = 0;
  auto alloc = [&](size_t bytes) {
    size_t o = off;
    off += (bytes + 255) & ~(size_t)255;
    return o;
  };

  double* xn64    = (double*)(ws + alloc((size_t)BN * C_ * 8));
  bf16*   xnb     = (bf16*)(ws + alloc((size_t)BN * C_ * 2));
  float*  qkv32   = (float*)(ws + alloc((size_t)BN * QKVC * 4));
  double* vnorm2  = (double*)(ws + alloc((size_t)BN * 8));
  double* q064    = (double*)(ws + alloc((size_t)B_ * C_ * 8));
  double* g64     = (double*)(ws + alloc((size_t)B_ * H_ * C_ * 8));
  double* l64     = (double*)(ws + alloc((size_t)B_ * H_ * N_ * 8));
  int*    selidx  = (int*)(ws + alloc((size_t)BT * 4));
  float*  poln    = (float*)(ws + alloc((size_t)BT * 4));
  bf16*   attn_bf = (bf16*)(ws + alloc((size_t)BT * C_ * 2));
  float*  cbuf    = (float*)(ws + alloc((size_t)BT * C_ * 4));
  float*  x2      = (float*)(ws + alloc((size_t)BT * C_ * 4));
  bf16*   qkvw_t  = (bf16*)(ws + alloc((size_t)QKVC * C_ * 2));
  bf16*   projw_t = (bf16*)(ws + alloc((size_t)C_ * C_ * 2));
  bf16*   fc1w_t  = (bf16*)(ws + alloc((size_t)4 * C_ * C_ * 2));
  bf16*   fc2w_t  = (bf16*)(ws + alloc((size_t)C_ * 4 * C_ * 2));
  bf16*   xn2b    = (bf16*)(ws + alloc((size_t)BT * C_ * 2));
  bf16*   h_bf    = (bf16*)(ws + alloc((size_t)BT * 4 * C_ * 2));
  if (off > ws_size) return;

  float* out_x = (float*)d_out;
  float* out_p = out_x + (size_t)BT * C_;

  transpose_bf16<<<dim3(QKVC / 32, C_ / 32), 256, 0, stream>>>(qkvw, qkvw_t, C_, QKVC);
  transpose_bf16<<<dim3(C_ / 32, C_ / 32), 256, 0, stream>>>(projw, projw_t, C_, C_);
  transpose_bf16<<<dim3(4 * C_ / 32, C_ / 32), 256, 0, stream>>>(fc1w, fc1w_t, C_, 4 * C_);
  transpose_bf16<<<dim3(C_ / 32, 4 * C_ / 32), 256, 0, stream>>>(fc2w, fc2w_t, 4 * C_, C_);

  ln1_kernel<<<BN, 256, 0, stream>>>(x, n1w, n1b, xn64, xnb);

  {
    dim3 g(QKVC / 128, (BN + 127) / 128);
    gemm128<<<g, 256, 0, stream>>>(xnb, qkvw_t, qkv32, nullptr, policy, BN, C_, QKVC, nullptr);
  }

  // fp64 scoring path
  q0_kernel<<<dim3(B_, C_ / 64), 256, 0, stream>>>(xn64, qkvw, policy, q064);
  g_kernel<<<B_ * H_, 256, 0, stream>>>(q064, qkvw, g64);
  logits_kernel<<<BN, 256, 0, stream>>>(xn64, g64, policy, l64);
  vnorm_kernel<<<BN / 8, 256, 0, stream>>>(xn64, qkvw, policy, vnorm2);
  softmax0_kernel<<<B_ * H_, 256, 0, stream>>>(l64, policy);
  select_kernel<<<B_, 1024, 0, stream>>>(l64, vnorm2, selidx, poln, out_p);

  // fused attention (bf16 MFMA QK^T + softmax-with-policy + MFMA PV)
  {
    dim3 g((NT_ + 63) / 64, B_ * H_);
    flash_kernel<<<g, 256, 0, stream>>>(qkv32, selidx, policy, attn_bf);
  }

  {
    dim3 g(C_ / 128, (BT + 127) / 128);
    gemm128<<<g, 256, 0, stream>>>(attn_bf, projw_t, cbuf, projb, nullptr, BT, C_, C_, nullptr);
  }
  e2_kernel<<<BT, 256, 0, stream>>>(cbuf, poln, selidx, x, x2);
  ln2_kernel<<<BT, 256, 0, stream>>>(x2, n2w, n2b, xn2b);
  {
    dim3 g(4 * C_ / 128, (BT + 127) / 128);
    gemm128<<<g, 256, 0, stream>>>(xn2b, fc1w_t, nullptr, fc1b, nullptr, BT, C_, 4 * C_, h_bf);
  }
  {
    dim3 g(C_ / 128, (BT + 127) / 128);
    gemm128<<<g, 256, 0, stream>>>(h_bf, fc2w_t, cbuf, fc2b, nullptr, BT, 4 * C_, C_, nullptr);
  }
  e4_kernel<<<BT, 256, 0, stream>>>(x2, cbuf, poln, out_x);
}

// Round 10
// 886.699 us; speedup vs baseline: 1.0415x; 1.0415x over previous
//
#include <hip/hip_runtime.h>
#include <hip/hip_bf16.h>
#include <float.h>
#include <math.h>
#include <stdint.h>

constexpr int B_   = 8;
constexpr int N_   = 785;
constexpr int C_   = 768;
constexpr int H_   = 12;
constexpr int DH_  = 64;
constexpr int NT_  = 393;
constexpr int QKVC = 3 * C_;   // 2304
constexpr int BN   = B_ * N_;  // 6280
constexpr int BT   = B_ * NT_; // 3144
constexpr int MSEL = N_ - 1;   // 784
constexpr float  SCALE_F = 0.125f;
constexpr double LNEPS   = 1e-5;
constexpr double SMEPS   = 1e-6;

#define DEV static __device__ __forceinline__

typedef __hip_bfloat16 bf16;
typedef __attribute__((ext_vector_type(8))) short frag8;
typedef __attribute__((ext_vector_type(4))) float facc4;

DEV short f2b(float v) { return (short)__hip_bfloat16_raw(__float2bfloat16(v)).x; }
DEV float b2f(short s) {
  union { unsigned int u; float f; } cv;
  cv.u = ((unsigned int)(unsigned short)s) << 16;
  return cv.f;
}
DEV float gelu_exact(float v) { return 0.5f * v * (1.0f + erff(v * 0.70710678118654752f)); }

// ---------------- block reductions ----------------
DEV double blockReduceSumD(double v, double* scratch, int nw) {
#pragma unroll
  for (int o = 32; o; o >>= 1) v += __shfl_xor(v, o);
  int lane = threadIdx.x & 63, wid = threadIdx.x >> 6;
  __syncthreads();
  if (lane == 0) scratch[wid] = v;
  __syncthreads();
  double r = scratch[0];
  for (int i = 1; i < nw; i++) r += scratch[i];
  return r;
}
DEV double blockReduceMaxD(double v, double* scratch, int nw) {
#pragma unroll
  for (int o = 32; o; o >>= 1) v = fmax(v, __shfl_xor(v, o));
  int lane = threadIdx.x & 63, wid = threadIdx.x >> 6;
  __syncthreads();
  if (lane == 0) scratch[wid] = v;
  __syncthreads();
  double r = scratch[0];
  for (int i = 1; i < nw; i++) r = fmax(r, scratch[i]);
  return r;
}
DEV float blockReduceSumF(float v, float* scratch, int nw) {
#pragma unroll
  for (int o = 32; o; o >>= 1) v += __shfl_xor(v, o);
  int lane = threadIdx.x & 63, wid = threadIdx.x >> 6;
  __syncthreads();
  if (lane == 0) scratch[wid] = v;
  __syncthreads();
  float r = scratch[0];
  for (int i = 1; i < nw; i++) r += scratch[i];
  return r;
}
DEV float blockReduceMaxF(float v, float* scratch, int nw) {
#pragma unroll
  for (int o = 32; o; o >>= 1) v = fmaxf(v, __shfl_xor(v, o));
  int lane = threadIdx.x & 63, wid = threadIdx.x >> 6;
  __syncthreads();
  if (lane == 0) scratch[wid] = v;
  __syncthreads();
  float r = scratch[0];
  for (int i = 1; i < nw; i++) r = fmaxf(r, scratch[i]);
  return r;
}

// ---------------- LN1: x(f32) -> xn64 (fp64 scoring) + xn_bf (bf16 value) --------
__global__ __launch_bounds__(256) void ln1_kernel(
    const float* __restrict__ x, const float* __restrict__ w, const float* __restrict__ b,
    double* __restrict__ xn64, bf16* __restrict__ xnb) {
  int row = blockIdx.x;
  int t = threadIdx.x;
  __shared__ double scr[8];
  const float* xr = x + (size_t)row * C_;
  double vals[3];
#pragma unroll
  for (int i = 0; i < 3; i++) vals[i] = (double)xr[t + i * 256];
  double s = vals[0] + vals[1] + vals[2];
  s = blockReduceSumD(s, scr, 4);
  double mean = s / (double)C_;
  double vs = 0.0;
#pragma unroll
  for (int i = 0; i < 3; i++) { double d = vals[i] - mean; vs += d * d; }
  vs = blockReduceSumD(vs, scr, 4);
  double inv = 1.0 / sqrt(vs / (double)C_ + LNEPS);
#pragma unroll
  for (int i = 0; i < 3; i++) {
    int c = t + i * 256;
    double o = (vals[i] - mean) * inv * (double)w[c] + (double)b[c];
    xn64[(size_t)row * C_ + c] = o;
    xnb[(size_t)row * C_ + c] = __float2bfloat16((float)o);
  }
}

// ---------------- weight transpose+convert: W[K][N] f32 -> Wt[N][K] bf16 ---------
__global__ __launch_bounds__(256) void transpose_bf16(
    const float* __restrict__ W, bf16* __restrict__ Wt, int K, int N) {
  __shared__ float tile[32][33];
  int k0 = blockIdx.y * 32, n0 = blockIdx.x * 32;
  int tx = threadIdx.x & 31, ty = threadIdx.x >> 5;
  for (int i = ty; i < 32; i += 8) {
    int k = k0 + i, n = n0 + tx;
    tile[i][tx] = (k < K && n < N) ? W[(size_t)k * N + n] : 0.f;
  }
  __syncthreads();
  for (int i = ty; i < 32; i += 8) {
    int n = n0 + i, k = k0 + tx;
    if (n < N && k < K) Wt[(size_t)n * K + k] = __float2bfloat16(tile[tx][i]);
  }
}

// ---------------- 64x64-tile bf16 MFMA GEMM with fused epilogues ----------------
// mode 0: Cc = (acc + bias) * rowscale             (plain; qkv-style)
// mode 1: Cc = gather(x,selidx) + (acc+bias)*poln  (proj + e2 -> x2)
// mode 2: Cc = res + (acc+bias)*poln               (fc2 + e4 -> out)
__global__ __launch_bounds__(256) void gemm_bf16(
    const bf16* __restrict__ A, const bf16* __restrict__ Bt,
    float* __restrict__ Cc, const float* __restrict__ bias,
    const float* __restrict__ rowscale, int M, int K, int Ncols,
    int mode, const float* __restrict__ xg, const int* __restrict__ selidx_,
    const float* __restrict__ poln_, const float* __restrict__ res) {
  __shared__ short As[64][40];
  __shared__ short Bs[64][40];
  const short* Ap = (const short*)A;
  const short* Bp = (const short*)Bt;
  int t = threadIdx.x;
  int n0 = blockIdx.x * 64;
  int m0 = blockIdx.y * 64;
  int w = t >> 6, l = t & 63;
  int srow = t >> 2;
  int koff = (t & 3) * 8;
  facc4 acc[4] = {{0, 0, 0, 0}, {0, 0, 0, 0}, {0, 0, 0, 0}, {0, 0, 0, 0}};
  int frow = (l & 15);
  int fk = (l >> 4) * 8;
  for (int k0 = 0; k0 < K; k0 += 32) {
    {
      int4 av = make_int4(0, 0, 0, 0);
      if (m0 + srow < M)
        av = *(const int4*)(Ap + (size_t)(m0 + srow) * K + k0 + koff);
      *(int4*)(&As[srow][koff]) = av;
      int4 bv = *(const int4*)(Bp + (size_t)(n0 + srow) * K + k0 + koff);
      *(int4*)(&Bs[srow][koff]) = bv;
    }
    __syncthreads();
    frag8 a = *(frag8*)(&As[w * 16 + frow][fk]);
#pragma unroll
    for (int nt = 0; nt < 4; nt++) {
      frag8 bfr = *(frag8*)(&Bs[nt * 16 + frow][fk]);
      acc[nt] = __builtin_amdgcn_mfma_f32_16x16x32_bf16(a, bfr, acc[nt], 0, 0, 0);
    }
    __syncthreads();
  }
#pragma unroll
  for (int reg = 0; reg < 4; reg++) {
    int row = m0 + w * 16 + (l >> 4) * 4 + reg;
    if (row >= M) continue;
    float rs = (mode == 0 && rowscale) ? rowscale[row] : 1.f;
    float pn = (mode != 0) ? poln_[row] : 0.f;
    int rsel = (mode == 1) ? selidx_[row] : 0;
    int bI = (mode == 1) ? (row / NT_) : 0;
#pragma unroll
    for (int nt = 0; nt < 4; nt++) {
      int col = n0 + nt * 16 + (l & 15);
      float v = acc[nt][reg];
      if (bias) v += bias[col];
      float outv;
      if (mode == 0) {
        outv = v * rs;
      } else if (mode == 1) {
        float sx = (rsel >= 0) ? xg[(size_t)(bI * N_ + rsel) * C_ + col] : 0.f;
        outv = sx + v * pn;
      } else {
        outv = res[(size_t)row * Ncols + col] + v * pn;
      }
      Cc[(size_t)row * Ncols + col] = outv;
    }
  }
}

// ---------------- 128x128-tile bf16 MFMA GEMM (large-grid shapes) ----------------
__global__ __launch_bounds__(256) void gemm128(
    const bf16* __restrict__ A, const bf16* __restrict__ Bt,
    float* __restrict__ Cc, const float* __restrict__ bias,
    const float* __restrict__ rowscale, int M, int K, int Ncols,
    bf16* __restrict__ gelu_bf) {
  __shared__ short As[128][40];
  __shared__ short Bs[128][40];
  const short* Ap = (const short*)A;
  const short* Bp = (const short*)Bt;
  int t = threadIdx.x;
  int n0 = blockIdx.x * 128;
  int m0 = blockIdx.y * 128;
  int w = t >> 6, l = t & 63;
  int wr = w >> 1, wc = w & 1;
  int srow = t >> 1;
  int koff = (t & 1) * 16;
  int fr = l & 15, fk = (l >> 4) * 8;
  facc4 acc[4][4] = {};
  for (int k0 = 0; k0 < K; k0 += 32) {
    int4 av0 = make_int4(0, 0, 0, 0), av1 = make_int4(0, 0, 0, 0);
    if (m0 + srow < M) {
      const short* ap = Ap + (size_t)(m0 + srow) * K + k0 + koff;
      av0 = *(const int4*)ap;
      av1 = *(const int4*)(ap + 8);
    }
    const short* bp = Bp + (size_t)(n0 + srow) * K + k0 + koff;
    int4 bv0 = *(const int4*)bp;
    int4 bv1 = *(const int4*)(bp + 8);
    *(int4*)(&As[srow][koff])     = av0;
    *(int4*)(&As[srow][koff + 8]) = av1;
    *(int4*)(&Bs[srow][koff])     = bv0;
    *(int4*)(&Bs[srow][koff + 8]) = bv1;
    __syncthreads();
    frag8 af[4], bf[4];
#pragma unroll
    for (int i = 0; i < 4; i++) af[i] = *(frag8*)(&As[wr * 64 + i * 16 + fr][fk]);
#pragma unroll
    for (int j = 0; j < 4; j++) bf[j] = *(frag8*)(&Bs[wc * 64 + j * 16 + fr][fk]);
#pragma unroll
    for (int i = 0; i < 4; i++)
#pragma unroll
      for (int j = 0; j < 4; j++)
        acc[i][j] = __builtin_amdgcn_mfma_f32_16x16x32_bf16(af[i], bf[j], acc[i][j], 0, 0, 0);
    __syncthreads();
  }
#pragma unroll
  for (int i = 0; i < 4; i++) {
#pragma unroll
    for (int reg = 0; reg < 4; reg++) {
      int row = m0 + wr * 64 + i * 16 + (l >> 4) * 4 + reg;
      if (row >= M) continue;
      float rs = rowscale ? rowscale[row] : 1.f;
#pragma unroll
      for (int j = 0; j < 4; j++) {
        int col = n0 + wc * 64 + j * 16 + fr;
        float v = acc[i][j][reg];
        if (bias) v += bias[col];
        if (gelu_bf) {
          gelu_bf[(size_t)row * Ncols + col] = __float2bfloat16(gelu_exact(v));
        } else {
          v *= rs;
          Cc[(size_t)row * Ncols + col] = v;
        }
      }
    }
  }
}

// ---------------- q0 (row-0 query, fp64): grid (B, 12), coalesced W reads --------
__global__ __launch_bounds__(256) void q0_kernel(
    const double* __restrict__ xn64, const float* __restrict__ qkvw,
    const float* __restrict__ policy, double* __restrict__ q064) {
  int b = blockIdx.x;
  int jc = blockIdx.y;             // 0..11 -> 64 outputs
  int t = threadIdx.x;
  int jl = t & 63, ks = t >> 6;    // 4 k-slices of 192
  __shared__ double x0[C_];
  __shared__ double part[4][64];
  for (int i = t; i < C_; i += 256) x0[i] = xn64[(size_t)(b * N_) * C_ + i];
  __syncthreads();
  int j = jc * 64 + jl;
  const float* wp = qkvw + j;
  double a = 0.0;
  int c0 = ks * 192;
#pragma unroll 8
  for (int c = c0; c < c0 + 192; c++) a += x0[c] * (double)wp[(size_t)c * QKVC];
  part[ks][jl] = a;
  __syncthreads();
  if (t < 64) {
    double pol = (double)policy[b * N_];
    q064[b * C_ + jc * 64 + t] =
        (part[0][t] + part[1][t] + part[2][t] + part[3][t]) * pol;
  }
}

// ---------------- g[b,h,c] (fp64) ----------------
__global__ __launch_bounds__(256) void g_kernel(
    const double* __restrict__ q064, const float* __restrict__ qkvw,
    double* __restrict__ g64) {
  int bh = blockIdx.x;
  int b = bh / H_, h = bh % H_;
  int t = threadIdx.x;
  __shared__ double qh[DH_];
  if (t < DH_) qh[t] = q064[b * C_ + h * DH_ + t];
  __syncthreads();
  for (int c = t; c < C_; c += 256) {
    const float* wp = qkvw + (size_t)c * QKVC + C_ + h * DH_;
    double a = 0.0;
#pragma unroll 8
    for (int d = 0; d < DH_; d++) a += qh[d] * (double)wp[d];
    g64[(size_t)bh * C_ + c] = a;
  }
}

// ---------------- row-0 logits fp64: wave-per-head, shuffle reduce ---------------
__global__ __launch_bounds__(256) void logits_kernel(
    const double* __restrict__ xn64, const double* __restrict__ g64,
    const float* __restrict__ policy, double* __restrict__ l64) {
  int row = blockIdx.x;
  int b = row / N_;
  int n = row % N_;
  int t = threadIdx.x;
  int w = t >> 6, lane = t & 63;
  __shared__ double xr[C_];
  for (int i = t; i < C_; i += 256) xr[i] = xn64[(size_t)row * C_ + i];
  __syncthreads();
  double pol = (double)policy[row];
#pragma unroll
  for (int hh = 0; hh < 3; hh++) {
    int h = w + hh * 4;
    const double* gp = g64 + (size_t)(b * H_ + h) * C_;
    double p = 0.0;
#pragma unroll 4
    for (int i = lane; i < C_; i += 64) p += xr[i] * gp[i];
#pragma unroll
    for (int o = 32; o; o >>= 1) p += __shfl_xor(p, o);
    if (lane == 0) l64[(size_t)(b * H_ + h) * N_ + n] = 0.125 * pol * p;
  }
}

// ---------------- ||v||^2 fp64: verified round-4 kernel (fp64 roofline ~253us) ---
__global__ __launch_bounds__(256) void vnorm_kernel(
    const double* __restrict__ xn64, const float* __restrict__ qkvw,
    const float* __restrict__ policy, double* __restrict__ vnorm2) {
  __shared__ double scr[8];
  int r0 = blockIdx.x * 8;
  int t = threadIdx.x;
  double acc[8][3] = {};
  const double* xb = xn64 + (size_t)r0 * C_;
  for (int c = 0; c < C_; c += 2) {
    const float* wp0 = qkvw + (size_t)c * QKVC + 2 * C_;
    const float* wp1 = wp0 + QKVC;
    double w00 = (double)wp0[t], w01 = (double)wp0[t + 256], w02 = (double)wp0[t + 512];
    double w10 = (double)wp1[t], w11 = (double)wp1[t + 256], w12 = (double)wp1[t + 512];
#pragma unroll
    for (int r = 0; r < 8; r++) {
      double x0 = xb[(size_t)r * C_ + c];
      double x1 = xb[(size_t)r * C_ + c + 1];
      acc[r][0] += x0 * w00; acc[r][1] += x0 * w01; acc[r][2] += x0 * w02;
      acc[r][0] += x1 * w10; acc[r][1] += x1 * w11; acc[r][2] += x1 * w12;
    }
  }
#pragma unroll
  for (int r = 0; r < 8; r++) {
    double p = acc[r][0] * acc[r][0] + acc[r][1] * acc[r][1] + acc[r][2] * acc[r][2];
    double s = blockReduceSumD(p, scr, 4);
    if (t == 0) {
      double pol = (double)policy[r0 + r];
      vnorm2[r0 + r] = s * pol * pol;
    }
  }
}

// ---------------- row-0 softmax fp64 (in place) ----------------
__global__ __launch_bounds__(256) void softmax0_kernel(
    double* __restrict__ l64, const float* __restrict__ policy) {
  int bh = blockIdx.x;
  int b = bh / H_;
  double* lp = l64 + (size_t)bh * N_;
  __shared__ double scr[8];
  int t = threadIdx.x;
  double mx = -1e300;
  for (int n = t; n < N_; n += 256) mx = fmax(mx, lp[n]);
  mx = blockReduceMaxD(mx, scr, 4);
  double ssum = 0.0;
  for (int n = t; n < N_; n += 256) {
    double pol = (double)policy[b * N_ + n];
    double w = (n == 0) ? 1.0 : pol;
    double e = exp(lp[n] - mx) * w;
    lp[n] = e;
    ssum += e;
  }
  ssum = blockReduceSumD(ssum, scr, 4);
  double denom = ssum + SMEPS;
  double addc = SMEPS / (double)N_;
  for (int n = t; n < N_; n += 256) lp[n] = (lp[n] + addc) / denom;
}

// ---------------- selection fp64, paranoid-simple ----------------
__global__ __launch_bounds__(1024) void select_kernel(
    const double* __restrict__ p0, const double* __restrict__ vnorm2,
    int* __restrict__ selidx, float* __restrict__ poln, float* __restrict__ out_pol) {
  int b = blockIdx.x;
  int t = threadIdx.x;
  __shared__ double sigv[MSEL];
  __shared__ double svals[MSEL];
  __shared__ double nc[MSEL];
  __shared__ int    ord[MSEL];
  __shared__ int    pick[MSEL];
  __shared__ int    spick[MSEL];
  __shared__ int    uq[MSEL];
  __shared__ int    suq[MSEL];
  __shared__ double sh_ys;

  if (t < MSEL) {
    int n = t + 1;
    double s = 0.0;
#pragma unroll
    for (int h = 0; h < H_; h++) s += p0[(size_t)(b * H_ + h) * N_ + n];
    sigv[t] = s * sqrt(vnorm2[b * N_ + n]);
  }
  __syncthreads();
  if (t < MSEL) {
    double v = sigv[t];
    int rank = 0;
    for (int i = 0; i < MSEL; i++) {
      double vi = sigv[i];
      rank += (vi < v) || (vi == v && i < t);
    }
    ord[rank] = t;
    svals[rank] = v;
  }
  __syncthreads();
  if (t == 0) {
    double a = 0.0;
    for (int i = 0; i < MSEL; i++) { a += svals[i]; svals[i] = a; }
  }
  __syncthreads();
  {
    double c0 = svals[0], cN = svals[MSEL - 1];
    if (t < MSEL) nc[t] = (svals[t] - c0) / (cN - c0);
  }
  __syncthreads();
  if (t == 0) {
    double m = 1e300;
    for (int i = 0; i < MSEL; i++) {
      double v = nc[i];
      if (v == 0.0) v += 100000000.0;
      m = fmin(m, v);
    }
    sh_ys = m;
  }
  __syncthreads();
  if (t < MSEL) {
    double s = sh_ys;
    double ysj = (t == MSEL - 1) ? 1.0 : (double)t / 783.0;
    double y = s + (ysj * 783.0 - s * (double)t) / 783.0;
    double bd = 1e300;
    int bi = 0;
    for (int i = 0; i < MSEL; i++) {
      double d = fabs(y - nc[i]);
      if (d < bd) { bd = d; bi = i; }
    }
    pick[t] = bi;
  }
  __syncthreads();
  if (t < MSEL) {
    int p = pick[t];
    int rank = 0;
    for (int i = 0; i < MSEL; i++) {
      int pi = pick[i];
      rank += (pi < p) || (pi == p && i < t);
    }
    spick[rank] = p;
  }
  __syncthreads();
  if (t < MSEL) {
    int s = spick[t];
    int nxt = (t < MSEL - 1) ? spick[t + 1] : 1;
    uq[t] = (nxt == s) ? MSEL : s;
  }
  __syncthreads();
  if (t < MSEL) {
    int u = uq[t];
    int rank = 0;
    for (int i = 0; i < MSEL; i++) {
      int ui = uq[i];
      rank += (ui < u) || (ui == u && i < t);
    }
    suq[rank] = u;
  }
  __syncthreads();
  if (t < NT_) {
    int sel, polI;
    if (t == 0) { sel = 0; polI = 1; }
    else {
      int ut = suq[t - 1];
      polI = (ut != MSEL) ? 1 : 0;
      sel = polI ? (ord[ut] + 1) : -1;
    }
    selidx[b * NT_ + t] = sel;
    poln[b * NT_ + t] = (float)polI;
    out_pol[b * NT_ + t] = (float)polI;
  }
}

// ---------------- fused flash attention, bf16 MFMA ----------------
__global__ __launch_bounds__(256) void flash_kernel(
    const float* __restrict__ qkv, const int* __restrict__ selidx,
    const float* __restrict__ policy, bf16* __restrict__ attn_bf) {
  int bh = blockIdx.y;
  int b = bh / H_, h = bh % H_;
  int j0 = blockIdx.x * 64;
  int t = threadIdx.x;
  int w = t >> 6, l = t & 63;
  __shared__ short Qs[64][72];   // [j][d]  A-operand layout
  __shared__ short Ks[64][72];   // [n][d]  B-operand layout (Bt-style)
  __shared__ short Ps[64][72];   // [j][n]  A-operand for PV
  __shared__ short Vs[64][72];   // [d][n]  B-operand for PV (V transposed)
  __shared__ float pol_s[64];
  __shared__ float Vsum[64];

  {
    int jr = t >> 2, d0 = (t & 3) * 16;
    int j = j0 + jr;
    int r = (j < NT_) ? selidx[b * NT_ + j] : -1;
    if (r < 0) r = 0;
    const float* qp = qkv + (size_t)(b * N_ + r) * QKVC + h * DH_ + d0;
#pragma unroll
    for (int i = 0; i < 16; i++) Qs[jr][d0 + i] = f2b(qp[i]);
  }
  if (t < 64) Vsum[t] = 0.f;

  int frow = l & 15, fk = (l >> 4) * 8;
  int base_r = w * 16 + (l >> 4) * 4;
  int coln = l & 15;

  int rrow[4];
#pragma unroll
  for (int r = 0; r < 4; r++) {
    int j = j0 + base_r + r;
    rrow[r] = (j < NT_) ? selidx[b * NT_ + j] : -1;
  }
  float m_run[4] = {-1e30f, -1e30f, -1e30f, -1e30f};
  float s_run[4] = {0.f, 0.f, 0.f, 0.f};
  facc4 Oacc[4] = {{0, 0, 0, 0}, {0, 0, 0, 0}, {0, 0, 0, 0}, {0, 0, 0, 0}};

  for (int n0 = 0; n0 < 832; n0 += 64) {
    {  // stage K tile
      int nr = t >> 2, d0 = (t & 3) * 16;
      int n = n0 + nr;
      bool ok = n < N_;
      const float* kp = qkv + (size_t)(b * N_ + (ok ? n : 0)) * QKVC + C_ + h * DH_ + d0;
#pragma unroll
      for (int i = 0; i < 16; i++) Ks[nr][d0 + i] = f2b(ok ? kp[i] : 0.f);
    }
    if (t < 64) {
      int n = n0 + t;
      pol_s[t] = (n < N_) ? policy[b * N_ + n] : 0.f;
    }
    __syncthreads();  // B1: K/pol visible (and prev-tile PV fully done)

    facc4 Sacc[4] = {{0, 0, 0, 0}, {0, 0, 0, 0}, {0, 0, 0, 0}, {0, 0, 0, 0}};
#pragma unroll
    for (int k0 = 0; k0 < 64; k0 += 32) {
      frag8 a = *(frag8*)(&Qs[w * 16 + frow][k0 + fk]);
#pragma unroll
      for (int nt = 0; nt < 4; nt++) {
        frag8 bb = *(frag8*)(&Ks[nt * 16 + frow][k0 + fk]);
        Sacc[nt] = __builtin_amdgcn_mfma_f32_16x16x32_bf16(a, bb, Sacc[nt], 0, 0, 0);
      }
    }
    float S[4][4];
    float tmax[4] = {-1e30f, -1e30f, -1e30f, -1e30f};
#pragma unroll
    for (int nt = 0; nt < 4; nt++) {
#pragma unroll
      for (int r = 0; r < 4; r++) {
        int n = n0 + nt * 16 + coln;
        float v = (n < N_) ? Sacc[nt][r] * SCALE_F : -1e30f;
        S[nt][r] = v;
        tmax[r] = fmaxf(tmax[r], v);
      }
    }
#pragma unroll
    for (int o = 1; o < 16; o <<= 1) {
#pragma unroll
      for (int r = 0; r < 4; r++) tmax[r] = fmaxf(tmax[r], __shfl_xor(tmax[r], o));
    }
    float m_new[4], scl[4], psum[4];
#pragma unroll
    for (int r = 0; r < 4; r++) {
      m_new[r] = fmaxf(m_run[r], tmax[r]);
      scl[r] = expf(m_run[r] - m_new[r]);
      psum[r] = 0.f;
    }
#pragma unroll
    for (int nt = 0; nt < 4; nt++) {
      float pol = pol_s[nt * 16 + coln];
      int n = n0 + nt * 16 + coln;
#pragma unroll
      for (int r = 0; r < 4; r++) {
        float wgt = (n == rrow[r]) ? 1.f : pol;
        float e = expf(S[nt][r] - m_new[r]) * wgt;
        S[nt][r] = e;
        psum[r] += e;
      }
    }
#pragma unroll
    for (int o = 1; o < 16; o <<= 1) {
#pragma unroll
      for (int r = 0; r < 4; r++) psum[r] += __shfl_xor(psum[r], o);
    }
#pragma unroll
    for (int r = 0; r < 4; r++) {
      s_run[r] = s_run[r] * scl[r] + psum[r];
      m_run[r] = m_new[r];
    }
    __syncthreads();  // B2: QK reads of Ks done; Ps/Vs free to overwrite

#pragma unroll
    for (int nt = 0; nt < 4; nt++) {
#pragma unroll
      for (int r = 0; r < 4; r++) Ps[base_r + r][nt * 16 + coln] = f2b(S[nt][r]);
    }
    {  // stage V transposed [d][n]
      int nr = t >> 2, d0 = (t & 3) * 16;
      int n = n0 + nr;
      bool ok = n < N_;
      const float* vp = qkv + (size_t)(b * N_ + (ok ? n : 0)) * QKVC + 2 * C_ + h * DH_ + d0;
#pragma unroll
      for (int i = 0; i < 16; i++) Vs[d0 + i][nr] = f2b(ok ? vp[i] : 0.f);
    }
    __syncthreads();  // B3: Ps/Vs visible

    if (t < 64) {
      float a = 0.f;
#pragma unroll 16
      for (int k = 0; k < 64; k++) a += b2f(Vs[t][k]);
      Vsum[t] += a;
    }
#pragma unroll
    for (int dt = 0; dt < 4; dt++) {
#pragma unroll
      for (int r = 0; r < 4; r++) Oacc[dt][r] *= scl[r];
    }
#pragma unroll
    for (int k0 = 0; k0 < 64; k0 += 32) {
      frag8 a = *(frag8*)(&Ps[w * 16 + frow][k0 + fk]);
#pragma unroll
      for (int dt = 0; dt < 4; dt++) {
        frag8 bb = *(frag8*)(&Vs[dt * 16 + frow][k0 + fk]);
        Oacc[dt] = __builtin_amdgcn_mfma_f32_16x16x32_bf16(a, bb, Oacc[dt], 0, 0, 0);
      }
    }
  }
  __syncthreads();  // Vsum final values visible to all
  float addc = 1e-6f / (float)N_;
#pragma unroll
  for (int r = 0; r < 4; r++) {
    int j = j0 + base_r + r;
    if (j >= NT_) continue;
    float denom = s_run[r] + 1e-6f;
#pragma unroll
    for (int dt = 0; dt < 4; dt++) {
      int d = dt * 16 + coln;
      float val = (Oacc[dt][r] + addc * Vsum[d]) / denom;
      attn_bf[(size_t)(b * NT_ + j) * C_ + h * DH_ + d] = __float2bfloat16(val);
    }
  }
}

// ---------------- epilogues ----------------
__global__ __launch_bounds__(256) void ln2_kernel(
    const float* __restrict__ xin, const float* __restrict__ w, const float* __restrict__ b,
    bf16* __restrict__ xoutb) {
  int row = blockIdx.x;
  int t = threadIdx.x;
  __shared__ float scr[8];
  const float* xr = xin + (size_t)row * C_;
  float vals[3];
#pragma unroll
  for (int i = 0; i < 3; i++) vals[i] = xr[t + i * 256];
  float s = vals[0] + vals[1] + vals[2];
  s = blockReduceSumF(s, scr, 4);
  float mean = s / (float)C_;
  float vs = 0.f;
#pragma unroll
  for (int i = 0; i < 3; i++) { float d = vals[i] - mean; vs += d * d; }
  vs = blockReduceSumF(vs, scr, 4);
  float sd = sqrtf(vs / (float)C_ + 1e-5f);
#pragma unroll
  for (int i = 0; i < 3; i++) {
    int c = t + i * 256;
    xoutb[(size_t)row * C_ + c] =
        __float2bfloat16((vals[i] - mean) / sd * w[c] + b[c]);
  }
}

// ---------------- launcher ----------------
extern "C" void kernel_launch(void* const* d_in, const int* in_sizes, int n_in,
                              void* d_out, int out_size, void* d_ws, size_t ws_size,
                              hipStream_t stream) {
  const float* x      = (const float*)d_in[0];
  const float* policy = (const float*)d_in[1];
  const float* n1w    = (const float*)d_in[2];
  const float* n1b    = (const float*)d_in[3];
  const float* qkvw   = (const float*)d_in[4];
  const float* projw  = (const float*)d_in[5];
  const float* projb  = (const float*)d_in[6];
  const float* n2w    = (const float*)d_in[7];
  const float* n2b    = (const float*)d_in[8];
  const float* fc1w   = (const float*)d_in[9];
  const float* fc1b   = (const float*)d_in[10];
  const float* fc2w   = (const float*)d_in[11];
  const float* fc2b   = (const float*)d_in[12];

  char* ws = (char*)d_ws;
  size_t off = 0;
  auto alloc = [&](size_t bytes) {
    size_t o = off;
    off += (bytes + 255) & ~(size_t)255;
    return o;
  };

  double* xn64    = (double*)(ws + alloc((size_t)BN * C_ * 8));
  bf16*   xnb     = (bf16*)(ws + alloc((size_t)BN * C_ * 2));
  float*  qkv32   = (float*)(ws + alloc((size_t)BN * QKVC * 4));
  double* vnorm2  = (double*)(ws + alloc((size_t)BN * 8));
  double* q064    = (double*)(ws + alloc((size_t)B_ * C_ * 8));
  double* g64     = (double*)(ws + alloc((size_t)B_ * H_ * C_ * 8));
  double* l64     = (double*)(ws + alloc((size_t)B_ * H_ * N_ * 8));
  int*    selidx  = (int*)(ws + alloc((size_t)BT * 4));
  float*  poln    = (float*)(ws + alloc((size_t)BT * 4));
  bf16*   attn_bf = (bf16*)(ws + alloc((size_t)BT * C_ * 2));
  float*  x2      = (float*)(ws + alloc((size_t)BT * C_ * 4));
  bf16*   qkvw_t  = (bf16*)(ws + alloc((size_t)QKVC * C_ * 2));
  bf16*   projw_t = (bf16*)(ws + alloc((size_t)C_ * C_ * 2));
  bf16*   fc1w_t  = (bf16*)(ws + alloc((size_t)4 * C_ * C_ * 2));
  bf16*   fc2w_t  = (bf16*)(ws + alloc((size_t)C_ * 4 * C_ * 2));
  bf16*   xn2b    = (bf16*)(ws + alloc((size_t)BT * C_ * 2));
  bf16*   h_bf    = (bf16*)(ws + alloc((size_t)BT * 4 * C_ * 2));
  if (off > ws_size) return;

  float* out_x = (float*)d_out;
  float* out_p = out_x + (size_t)BT * C_;

  transpose_bf16<<<dim3(QKVC / 32, C_ / 32), 256, 0, stream>>>(qkvw, qkvw_t, C_, QKVC);
  transpose_bf16<<<dim3(C_ / 32, C_ / 32), 256, 0, stream>>>(projw, projw_t, C_, C_);
  transpose_bf16<<<dim3(4 * C_ / 32, C_ / 32), 256, 0, stream>>>(fc1w, fc1w_t, C_, 4 * C_);
  transpose_bf16<<<dim3(C_ / 32, 4 * C_ / 32), 256, 0, stream>>>(fc2w, fc2w_t, 4 * C_, C_);

  ln1_kernel<<<BN, 256, 0, stream>>>(x, n1w, n1b, xn64, xnb);

  {  // qkv: large grid -> 128^2 tile
    dim3 g(QKVC / 128, (BN + 127) / 128);
    gemm128<<<g, 256, 0, stream>>>(xnb, qkvw_t, qkv32, nullptr, policy, BN, C_, QKVC, nullptr);
  }

  // fp64 scoring path
  q0_kernel<<<dim3(B_, C_ / 64), 256, 0, stream>>>(xn64, qkvw, policy, q064);
  g_kernel<<<B_ * H_, 256, 0, stream>>>(q064, qkvw, g64);
  logits_kernel<<<BN, 256, 0, stream>>>(xn64, g64, policy, l64);
  vnorm_kernel<<<BN / 8, 256, 0, stream>>>(xn64, qkvw, policy, vnorm2);
  softmax0_kernel<<<B_ * H_, 256, 0, stream>>>(l64, policy);
  select_kernel<<<B_, 1024, 0, stream>>>(l64, vnorm2, selidx, poln, out_p);

  // fused attention (bf16 MFMA QK^T + softmax-with-policy + MFMA PV)
  {
    dim3 g((NT_ + 63) / 64, B_ * H_);
    flash_kernel<<<g, 256, 0, stream>>>(qkv32, selidx, policy, attn_bf);
  }

  {  // proj + e2 fused: x2 = gather(x) + (acc+projb)*poln   (64^2: N=768 -> 600 blocks)
    dim3 g(C_ / 64, (BT + 63) / 64);
    gemm_bf16<<<g, 256, 0, stream>>>(attn_bf, projw_t, x2, projb, nullptr, BT, C_, C_,
                                     1, x, selidx, poln, nullptr);
  }
  ln2_kernel<<<BT, 256, 0, stream>>>(x2, n2w, n2b, xn2b);
  {  // fc1 + gelu fused (128^2: 24x25=600 blocks)
    dim3 g(4 * C_ / 128, (BT + 127) / 128);
    gemm128<<<g, 256, 0, stream>>>(xn2b, fc1w_t, nullptr, fc1b, nullptr, BT, C_, 4 * C_, h_bf);
  }
  {  // fc2 + e4 fused: out = x2 + (acc+fc2b)*poln   (64^2: N=768 -> 600 blocks)
    dim3 g(C_ / 64, (BT + 63) / 64);
    gemm_bf16<<<g, 256, 0, stream>>>(h_bf, fc2w_t, out_x, fc2b, nullptr, BT, 4 * C_, C_,
                                     2, nullptr, nullptr, poln, x2);
  }
}